// Round 4
// baseline (232.731 us; speedup 1.0000x reference)
//
#include <hip/hip_runtime.h>
#include <stdint.h>

// Problem constants (fixed by the reference):
#define N_ROWS 262144
#define DIM    128
#define HID    16
#define NEXP   21
// Segments of 64 rows, each expert's region padded up to a multiple of 64.
#define NSEG   (N_ROWS / 64 + NEXP)   // 4096 + 21 = 4117 worst case
#define NBLK1  256                    // blocks for hist/scatter
#define RPB    (N_ROWS / NBLK1)       // 1024 rows per block
#define RPT    (RPB / 256)            // 4 rows per thread

// k_main LDS staging: per wave, 8 blocks of 1 KB (one 128-B line of 8 rows
// each), padded +16 B so readback banks spread over all 32 banks.
#define PADB     1040                 // 1024 + 16
#define WAVE_LDS (8 * PADB)           // 8320 B per wave
#define BLK_LDS  (4 * WAVE_LDS)       // 33280 B per 256-thread block

// ---------------------------------------------------------------------------
// K1: per-block histogram of sid + reserve per-(block,expert) ranges.
// ---------------------------------------------------------------------------
__global__ __launch_bounds__(256) void k_hist(const int* __restrict__ sid,
                                              int* __restrict__ counts,
                                              int* __restrict__ blockBase) {
    __shared__ int lh[NEXP];
    int t = threadIdx.x;
    if (t < NEXP) lh[t] = 0;
    __syncthreads();
    int base = blockIdx.x * RPB + t;
#pragma unroll
    for (int r = 0; r < RPT; r++) {
        atomicAdd(&lh[sid[base + r * 256]], 1);
    }
    __syncthreads();
    if (t < NEXP) blockBase[blockIdx.x * NEXP + t] = atomicAdd(&counts[t], lh[t]);
}

// ---------------------------------------------------------------------------
// K2: scatter rows into per-expert 64-padded buckets.  Entry = row | (e<<24).
// Tail slots stay -1 (memset 0xFF).
// ---------------------------------------------------------------------------
__global__ __launch_bounds__(256) void k_scatter(const int* __restrict__ sid,
                                                 const int* __restrict__ counts,
                                                 const int* __restrict__ blockBase,
                                                 int* __restrict__ buckets) {
    __shared__ int sbase[NEXP];
    __shared__ int lcur[NEXP];
    int t = threadIdx.x;
    if (t == 0) {
        int acc = 0;
        for (int e = 0; e < NEXP; e++) {
            sbase[e] = acc + blockBase[blockIdx.x * NEXP + e];
            acc += ((counts[e] + 63) >> 6) << 6;   // pad each expert to 64
        }
    }
    if (t < NEXP) lcur[t] = 0;
    __syncthreads();
    int base = blockIdx.x * RPB + t;
#pragma unroll
    for (int r = 0; r < RPT; r++) {
        int row = base + r * 256;
        int e = sid[row];
        int lp = atomicAdd(&lcur[e], 1);
        buckets[sbase[e] + lp] = row | (e << 24);
    }
}

// ---------------------------------------------------------------------------
// K3: one wave per 64-row same-expert segment.
//
// Rounds 1-3 proved lane-per-row float4 gathers are pinned at ~1.9 TB/s by
// TA/TCP distinct-line request throughput (64 lines/instr x ~5cyc = 320 cyc
// -> 3.2 B/cyc/CU).  Fix: gather with 8 lanes per 128-B line (8 lines/instr,
// the m13 copy-kernel pattern) via global_load_lds (no VGPR staging -> the
// compiler cannot collapse the pipeline), then LDS-transpose back to
// lane-per-row so the W1 FMAs keep wave-uniform scalar-broadcast operands.
//
// LDS map (per wave, reused across 4 phases):  block g (=row group) at
// g*1040; staging instr (g,q) writes lane*16 (1 KB).  Readback lane L chunk
// (q local m): addr = (L>>3)*1040 + (L&7)*128 + m*16 -> banks 4*(L>>3) +
// spread -> conflict-free 8-cyc ds_read_b128.
// ---------------------------------------------------------------------------
typedef __attribute__((address_space(1))) const uint32_t gu32;
typedef __attribute__((address_space(3))) uint32_t lu32;

__device__ __forceinline__ void stage16(const float* gp, char* lp) {
    __builtin_amdgcn_global_load_lds((gu32*)(uintptr_t)gp,
                                     (lu32*)(uintptr_t)lp, 16, 0, 0);
}

__global__ __launch_bounds__(256, 4) void k_main3(const float* __restrict__ x,
                                                  const float* __restrict__ W1,
                                                  const float* __restrict__ b1,
                                                  const float* __restrict__ W2,
                                                  const float* __restrict__ b2,
                                                  const int* __restrict__ buckets,
                                                  float* __restrict__ out) {
    extern __shared__ char smem[];
    const int seg = blockIdx.x * 4 + (threadIdx.x >> 6);
    if (seg >= NSEG) return;                       // no barriers in this kernel
    const int lane = threadIdx.x & 63;
    char* waveLds = smem + (threadIdx.x >> 6) * WAVE_LDS;

    int ent = buckets[seg * 64 + lane];
    if (__ballot(ent >= 0) == 0ULL) return;        // wholly-empty tail segment
    // Valid slots form a prefix -> lane 0 valid -> e is wave-uniform.
    const int e = __builtin_amdgcn_readfirstlane(ent) >> 24;
    const int row = ent & 0x00FFFFFF;
    const int vrow = (ent >= 0) ? row : 0;         // invalid lanes: dup row 0

    // Row this lane stages for each group g: slot g*8 + (lane>>3).
    int rg[8];
#pragma unroll
    for (int g = 0; g < 8; g++) rg[g] = __shfl(vrow, g * 8 + (lane >> 3), 64);
    const int c8 = lane & 7;

    const float* __restrict__ w1 = W1 + e * (DIM * HID);
    float h[HID];
#pragma unroll
    for (int j = 0; j < HID; j++) h[j] = b1[e * HID + j];

    const char* rb = waveLds + (lane >> 3) * PADB + (lane & 7) * 128;

#pragma unroll
    for (int q = 0; q < 4; q++) {                  // 4 lines of 128 B per row
        __builtin_amdgcn_s_waitcnt(0);             // prev-phase reads done; buffer free
#pragma unroll
        for (int g = 0; g < 8; g++) {
            const float* gp = x + (size_t)rg[g] * DIM + q * 32 + c8 * 4;
            stage16(gp, waveLds + g * PADB + lane * 16);
        }
        __builtin_amdgcn_s_waitcnt(0);             // LDS-DMA complete -> visible
#pragma unroll
        for (int m = 0; m < 8; m++) {
            const float4 xv = *(const float4*)(rb + m * 16);  // ds_read_b128
            const int k0 = (q * 8 + m) * 4;
#pragma unroll
            for (int j = 0; j < HID; j++) h[j] = fmaf(xv.x, w1[(k0 + 0) * HID + j], h[j]);
#pragma unroll
            for (int j = 0; j < HID; j++) h[j] = fmaf(xv.y, w1[(k0 + 1) * HID + j], h[j]);
#pragma unroll
            for (int j = 0; j < HID; j++) h[j] = fmaf(xv.z, w1[(k0 + 2) * HID + j], h[j]);
#pragma unroll
            for (int j = 0; j < HID; j++) h[j] = fmaf(xv.w, w1[(k0 + 3) * HID + j], h[j]);
        }
    }

    float acc = b2[e];
#pragma unroll
    for (int j = 0; j < HID; j++) acc = fmaf(fmaxf(h[j], 0.0f), W2[e * HID + j], acc);
    if (ent >= 0) out[row] = fmaxf(acc, 0.0f);
}

// ---------------------------------------------------------------------------
// Fallback (only if ws_size is too small for the buckets): thread-per-row.
// ---------------------------------------------------------------------------
__global__ __launch_bounds__(256) void k_naive(const float* __restrict__ x,
                                               const int* __restrict__ sid,
                                               const float* __restrict__ W1,
                                               const float* __restrict__ b1,
                                               const float* __restrict__ W2,
                                               const float* __restrict__ b2,
                                               float* __restrict__ out) {
    int row = blockIdx.x * 256 + threadIdx.x;
    if (row >= N_ROWS) return;
    int e = sid[row];
    const float* w1 = W1 + e * (DIM * HID);
    const float* xr = x + (size_t)row * DIM;
    float h[HID];
#pragma unroll
    for (int j = 0; j < HID; j++) h[j] = b1[e * HID + j];
    for (int k = 0; k < DIM; k++) {
        float xk = xr[k];
#pragma unroll
        for (int j = 0; j < HID; j++) h[j] = fmaf(xk, w1[k * HID + j], h[j]);
    }
    float acc = b2[e];
#pragma unroll
    for (int j = 0; j < HID; j++) acc = fmaf(fmaxf(h[j], 0.0f), W2[e * HID + j], acc);
    out[row] = fmaxf(acc, 0.0f);
}

extern "C" void kernel_launch(void* const* d_in, const int* in_sizes, int n_in,
                              void* d_out, int out_size, void* d_ws, size_t ws_size,
                              hipStream_t stream) {
    const float* x   = (const float*)d_in[0];
    const int*   sid = (const int*)d_in[1];
    const float* W1  = (const float*)d_in[2];
    const float* b1  = (const float*)d_in[3];
    const float* W2  = (const float*)d_in[4];
    const float* b2  = (const float*)d_in[5];
    float* out = (float*)d_out;

    // Workspace layout: buckets | counts(32) | blockBase(NBLK1*NEXP)
    const size_t bucketBytes = (size_t)NSEG * 64 * sizeof(int);
    const size_t countBytes  = 32 * sizeof(int);
    const size_t bbBytes     = (size_t)NBLK1 * NEXP * sizeof(int);
    const size_t need = bucketBytes + countBytes + bbBytes;

    if (ws_size < need) {
        k_naive<<<(N_ROWS + 255) / 256, 256, 0, stream>>>(x, sid, W1, b1, W2, b2, out);
        return;
    }

    char* ws = (char*)d_ws;
    int* buckets   = (int*)ws;
    int* counts    = (int*)(ws + bucketBytes);
    int* blockBase = (int*)(ws + bucketBytes + countBytes);

    hipMemsetAsync(buckets, 0xFF, bucketBytes, stream);   // all -1
    hipMemsetAsync(counts, 0, countBytes, stream);
    k_hist<<<NBLK1, 256, 0, stream>>>(sid, counts, blockBase);
    k_scatter<<<NBLK1, 256, 0, stream>>>(sid, counts, blockBase, buckets);
    k_main3<<<(NSEG + 3) / 4, 256, BLK_LDS, stream>>>(x, W1, b1, W2, b2, buckets, out);
}

// Round 5
// 221.350 us; speedup vs baseline: 1.0514x; 1.0514x over previous
//
#include <hip/hip_runtime.h>
#include <stdint.h>

// Problem constants (fixed by the reference):
#define N_ROWS 262144
#define DIM    128
#define HID    16
#define NEXP   21
// Segments of 64 rows, each expert's region padded up to a multiple of 64.
#define NSEG   (N_ROWS / 64 + NEXP)   // 4096 + 21 = 4117 worst case
#define NBLK1  256                    // blocks for hist/scatter
#define RPB    (N_ROWS / NBLK1)       // 1024 rows per block
#define RPT    (RPB / 256)            // 4 rows per thread

// k_main LDS staging: per wave, 8 blocks of 1 KB (one 128-B line of 8 rows
// each), padded +16 B so readback banks spread over all 32 banks.
#define PADB     1040                 // 1024 + 16
#define WAVE_LDS (8 * PADB)           // 8320 B per wave
#define BLK_LDS  (4 * WAVE_LDS)       // 33280 B per 256-thread block -> 4 blk/CU

// ---------------------------------------------------------------------------
// K1: per-block histogram of sid + reserve per-(block,expert) ranges.
// ---------------------------------------------------------------------------
__global__ __launch_bounds__(256) void k_hist(const int* __restrict__ sid,
                                              int* __restrict__ counts,
                                              int* __restrict__ blockBase) {
    __shared__ int lh[NEXP];
    int t = threadIdx.x;
    if (t < NEXP) lh[t] = 0;
    __syncthreads();
    int base = blockIdx.x * RPB + t;
#pragma unroll
    for (int r = 0; r < RPT; r++) {
        atomicAdd(&lh[sid[base + r * 256]], 1);
    }
    __syncthreads();
    if (t < NEXP) blockBase[blockIdx.x * NEXP + t] = atomicAdd(&counts[t], lh[t]);
}

// ---------------------------------------------------------------------------
// K2: scatter rows into per-expert 64-padded buckets.  Entry = row | (e<<24).
// Tail slots stay -1 (memset 0xFF).
// ---------------------------------------------------------------------------
__global__ __launch_bounds__(256) void k_scatter(const int* __restrict__ sid,
                                                 const int* __restrict__ counts,
                                                 const int* __restrict__ blockBase,
                                                 int* __restrict__ buckets) {
    __shared__ int sbase[NEXP];
    __shared__ int lcur[NEXP];
    int t = threadIdx.x;
    if (t == 0) {
        int acc = 0;
        for (int e = 0; e < NEXP; e++) {
            sbase[e] = acc + blockBase[blockIdx.x * NEXP + e];
            acc += ((counts[e] + 63) >> 6) << 6;   // pad each expert to 64
        }
    }
    if (t < NEXP) lcur[t] = 0;
    __syncthreads();
    int base = blockIdx.x * RPB + t;
#pragma unroll
    for (int r = 0; r < RPT; r++) {
        int row = base + r * 256;
        int e = sid[row];
        int lp = atomicAdd(&lcur[e], 1);
        buckets[sbase[e] + lp] = row | (e << 24);
    }
}

// ---------------------------------------------------------------------------
// K3 (round 5): one wave per 64-row same-expert segment.
//
// History: rounds 1-4 proved (by falsification) that neither x-load DEPTH
// (sched_barrier pipeline, r3: +8us) nor x-load COALESCING (global_load_lds
// staging, r4: +0us) was the binding constraint.  The never-changed component
// was the scalar W1 stream: 2048 floats/wave through <=102 SGPRs => ~128
// s_load_dwordx16 with ~2-3 outstanding at ~300cyc (K$ thrash across
// different-expert waves) => lgkm-serialized, ~same magnitude as the vm stall
// it alternates with.  Both must go at once.
//
// This kernel keeps the r4 coalesced LDS-staged x gather AND replaces scalar
// W1 with a VGPR-resident broadcast: per phase q, lane L caches
// w1[q*512 + m*64 + L] in wq[m] (8 coalesced 256-B dword loads, L2-hot);
// the FMA reads w1[k*16+j] via v_readlane_b32(wq[m], c*16+j) -- register
// index m and lane index are compile-time after unrolling; q stays a rolled
// loop so the ~1.1k-inst body fits I$.  Zero SMEM / zero LDS traffic for W1.
// ---------------------------------------------------------------------------
typedef __attribute__((address_space(1))) const uint32_t gu32;
typedef __attribute__((address_space(3))) uint32_t lu32;

__device__ __forceinline__ void stage16(const float* gp, char* lp) {
    __builtin_amdgcn_global_load_lds((gu32*)(uintptr_t)gp,
                                     (lu32*)(uintptr_t)lp, 16, 0, 0);
}

__device__ __forceinline__ float bcast(float v, int lane) {
    return __uint_as_float(__builtin_amdgcn_readlane(__float_as_uint(v), lane));
}

__global__ __launch_bounds__(256, 4) void k_main4(const float* __restrict__ x,
                                                  const float* __restrict__ W1,
                                                  const float* __restrict__ b1,
                                                  const float* __restrict__ W2,
                                                  const float* __restrict__ b2,
                                                  const int* __restrict__ buckets,
                                                  float* __restrict__ out) {
    extern __shared__ char smem[];
    const int seg = blockIdx.x * 4 + (threadIdx.x >> 6);
    if (seg >= NSEG) return;                       // no block barriers used
    const int lane = threadIdx.x & 63;
    char* waveLds = smem + (threadIdx.x >> 6) * WAVE_LDS;

    int ent = buckets[seg * 64 + lane];
    if (__ballot(ent >= 0) == 0ULL) return;        // wholly-empty tail segment
    // Valid slots form a prefix -> lane 0 valid -> e is wave-uniform.
    const int e = __builtin_amdgcn_readfirstlane(ent) >> 24;
    const int row = ent & 0x00FFFFFF;
    const int vrow = (ent >= 0) ? row : 0;         // invalid lanes: dup row 0

    // Row this lane stages for each group g: slot g*8 + (lane>>3).
    int rg[8];
#pragma unroll
    for (int g = 0; g < 8; g++) rg[g] = __shfl(vrow, g * 8 + (lane >> 3), 64);
    const int c8 = lane & 7;

    const float* __restrict__ w1 = W1 + e * (DIM * HID);
    float h[HID];
#pragma unroll
    for (int j = 0; j < HID; j++) h[j] = b1[e * HID + j];

    const char* rb = waveLds + (lane >> 3) * PADB + (lane & 7) * 128;

#pragma unroll 1
    for (int q = 0; q < 4; q++) {                  // 4 lines of 128 B per row
        __builtin_amdgcn_s_waitcnt(0);             // prev-phase LDS reuse safe
        // ---- issue the 8 coalesced staging loads (1 KB each, HBM) ----
#pragma unroll
        for (int g = 0; g < 8; g++) {
            const float* gp = x + (size_t)rg[g] * DIM + q * 32 + c8 * 4;
            stage16(gp, waveLds + g * PADB + lane * 16);
        }
        // ---- cache this phase's 512 W1 values across the wave (L2-hot) ----
        const float* __restrict__ w1q = w1 + q * 512;
        float wq[8];
#pragma unroll
        for (int m = 0; m < 8; m++) wq[m] = w1q[m * 64 + lane];  // 256B coalesced
        __builtin_amdgcn_s_waitcnt(0);             // staging + wq visible
#pragma unroll
        for (int m = 0; m < 8; m++) {
            const float4 xv = *(const float4*)(rb + m * 16);  // ds_read_b128
            const float xc[4] = {xv.x, xv.y, xv.z, xv.w};
#pragma unroll
            for (int c = 0; c < 4; c++) {
#pragma unroll
                for (int j = 0; j < HID; j++)
                    h[j] = fmaf(xc[c], bcast(wq[m], c * 16 + j), h[j]);
            }
        }
    }

    float acc = b2[e];
#pragma unroll
    for (int j = 0; j < HID; j++) acc = fmaf(fmaxf(h[j], 0.0f), W2[e * HID + j], acc);
    if (ent >= 0) out[row] = fmaxf(acc, 0.0f);
}

// ---------------------------------------------------------------------------
// Fallback (only if ws_size is too small for the buckets): thread-per-row.
// ---------------------------------------------------------------------------
__global__ __launch_bounds__(256) void k_naive(const float* __restrict__ x,
                                               const int* __restrict__ sid,
                                               const float* __restrict__ W1,
                                               const float* __restrict__ b1,
                                               const float* __restrict__ W2,
                                               const float* __restrict__ b2,
                                               float* __restrict__ out) {
    int row = blockIdx.x * 256 + threadIdx.x;
    if (row >= N_ROWS) return;
    int e = sid[row];
    const float* w1 = W1 + e * (DIM * HID);
    const float* xr = x + (size_t)row * DIM;
    float h[HID];
#pragma unroll
    for (int j = 0; j < HID; j++) h[j] = b1[e * HID + j];
    for (int k = 0; k < DIM; k++) {
        float xk = xr[k];
#pragma unroll
        for (int j = 0; j < HID; j++) h[j] = fmaf(xk, w1[k * HID + j], h[j]);
    }
    float acc = b2[e];
#pragma unroll
    for (int j = 0; j < HID; j++) acc = fmaf(fmaxf(h[j], 0.0f), W2[e * HID + j], acc);
    out[row] = fmaxf(acc, 0.0f);
}

extern "C" void kernel_launch(void* const* d_in, const int* in_sizes, int n_in,
                              void* d_out, int out_size, void* d_ws, size_t ws_size,
                              hipStream_t stream) {
    const float* x   = (const float*)d_in[0];
    const int*   sid = (const int*)d_in[1];
    const float* W1  = (const float*)d_in[2];
    const float* b1  = (const float*)d_in[3];
    const float* W2  = (const float*)d_in[4];
    const float* b2  = (const float*)d_in[5];
    float* out = (float*)d_out;

    // Workspace layout: buckets | counts(32) | blockBase(NBLK1*NEXP)
    const size_t bucketBytes = (size_t)NSEG * 64 * sizeof(int);
    const size_t countBytes  = 32 * sizeof(int);
    const size_t bbBytes     = (size_t)NBLK1 * NEXP * sizeof(int);
    const size_t need = bucketBytes + countBytes + bbBytes;

    if (ws_size < need) {
        k_naive<<<(N_ROWS + 255) / 256, 256, 0, stream>>>(x, sid, W1, b1, W2, b2, out);
        return;
    }

    char* ws = (char*)d_ws;
    int* buckets   = (int*)ws;
    int* counts    = (int*)(ws + bucketBytes);
    int* blockBase = (int*)(ws + bucketBytes + countBytes);

    hipMemsetAsync(buckets, 0xFF, bucketBytes, stream);   // all -1
    hipMemsetAsync(counts, 0, countBytes, stream);
    k_hist<<<NBLK1, 256, 0, stream>>>(sid, counts, blockBase);
    k_scatter<<<NBLK1, 256, 0, stream>>>(sid, counts, blockBase, buckets);
    k_main4<<<(NSEG + 3) / 4, 256, BLK_LDS, stream>>>(x, W1, b1, W2, b2, buckets, out);
}